// Round 7
// baseline (486.781 us; speedup 1.0000x reference)
//
#include <hip/hip_runtime.h>
#include <stdint.h>

// VectorQuantizer (eval fwd): inputs [64,64,32,32] f32 NCHW, embedding [1024,64] f32.
// Outputs concatenated: quantized [64,64,32,32] f32, loss scalar, perplexity scalar.
//
// Round-7 structure: single fused main kernel.
//  - x tile (64 rows x 64 ch) staged in LDS (stride 68 dwords: 16B-aligned rows,
//    uniform bank coverage for b128 reads).
//  - K split across the 4 waves of the block (wave w: codes [256w, 256w+256)).
//    All lanes of a wave scan the same code -> e loads wave-uniform -> s_load
//    (scalar pipe), FMAs read x chunks from LDS (small live set: acc[8]+xc[8]).
//  - Per-wave (best,k) lex-merged in LDS; epilogue (gather/STE/loss/counts)
//    fused in the same kernel off the resident x tile.
// Distance arithmetic: dist = ||e||^2 - 2 x.e (row-constant ||x||^2 dropped) --
// same formula that matched the reference argmin exactly in rounds 2/3/5/6.

#define K_CODES 1024
#define DIM 64
#define HW 1024          // 32*32
#define N_ROWS 65536
#define OUT_ELEMS 4194304
#define XSTR 68          // x row stride in dwords

// ws layout (float indices)
#define WS_E2   0        // 1024 f32: ||e_k||^2
#define WS_CNT  1024     // 1024 u32: counts
#define WS_LOSS 2048     // 1 f32

__global__ void vq_init(const float* __restrict__ emb, float* __restrict__ ws) {
    const int k = blockIdx.x * blockDim.x + threadIdx.x;  // 1024 threads total
    if (k < K_CODES) {
        const float4* e4 = reinterpret_cast<const float4*>(emb + k * DIM);
        float s = 0.f;
#pragma unroll
        for (int i = 0; i < DIM / 4; ++i) {
            float4 v = e4[i];
            s += v.x * v.x + v.y * v.y + v.z * v.z + v.w * v.w;
        }
        ws[WS_E2 + k] = s;
        reinterpret_cast<unsigned int*>(ws)[WS_CNT + k] = 0u;
    }
    if (blockIdx.x == 0 && threadIdx.x == 0) ws[WS_LOSS] = 0.f;
}

__global__ __launch_bounds__(256, 4) void vq_main(
    const float* __restrict__ in, const float* __restrict__ emb,
    float* __restrict__ out, float* __restrict__ ws)
{
    __shared__ __align__(16) float xs[64 * XSTR];   // 17408 B
    __shared__ float bwd[4][64];
    __shared__ int   bwk[4][64];
    __shared__ int   fk[64];
    __shared__ float lred[4];

    const int t = threadIdx.x;
    const int w = t >> 6;        // wave id -> k-range and channel-group
    const int l = t & 63;        // pixel-row within block
    const int row0 = blockIdx.x * 64;
    const int b = row0 >> 10, hw0 = row0 & 1023;
    const float* xin = in + b * (DIM * HW) + hw0;

    // ---- stage x tile: thread (w,l) loads channels [16w,16w+16) of row l ----
#pragma unroll
    for (int cc = 0; cc < 16; ++cc) {
        const int c = w * 16 + cc;
        xs[l * XSTR + c] = xin[c * HW + l];   // lanes l consecutive -> coalesced
    }
    __syncthreads();

    // ---- argmin over this wave's 256 codes ----
    const float* e2 = ws + WS_E2;
    const float* xrow = xs + l * XSTR;
    float best = 3.4e38f;
    int   bestk = 0;
    const int k0 = w * 256;

    for (int kg = 0; kg < 256; kg += 8) {
        float acc[8] = {0.f, 0.f, 0.f, 0.f, 0.f, 0.f, 0.f, 0.f};
#pragma unroll
        for (int ch = 0; ch < 8; ++ch) {
            float xc[8];
            *(float4*)(xc)     = *(const float4*)(xrow + ch * 8);      // ds_read_b128
            *(float4*)(xc + 4) = *(const float4*)(xrow + ch * 8 + 4);  // ds_read_b128
#pragma unroll
            for (int c = 0; c < 8; ++c) {
                const float* e = emb + (k0 + kg + c) * DIM + ch * 8;   // uniform -> s_load
#pragma unroll
                for (int j = 0; j < 8; ++j)
                    acc[c] = fmaf(e[j], xc[j], acc[c]);
            }
        }
#pragma unroll
        for (int c = 0; c < 8; ++c) {
            const int k = k0 + kg + c;
            const float dist = fmaf(-2.f, acc[c], e2[k]);
            if (dist < best) { best = dist; bestk = k; }   // strict < : first occurrence
        }
    }

    bwd[w][l] = best;
    bwk[w][l] = bestk;
    __syncthreads();

    // ---- lex-merge across the 4 waves (k-ranges ascending) ----
    if (t < 64) {
        float bb = bwd[0][t]; int bk = bwk[0][t];
#pragma unroll
        for (int s = 1; s < 4; ++s) {
            const float d = bwd[s][t]; const int k = bwk[s][t];
            if (d < bb || (d == bb && k < bk)) { bb = d; bk = k; }
        }
        fk[t] = bk;
        atomicAdd(reinterpret_cast<unsigned int*>(ws) + WS_CNT + bk, 1u);
    }
    __syncthreads();

    // ---- fused epilogue: thread (w,l): row l, channels [16w,16w+16) ----
    const int bk = fk[l];
    const float4* eq = reinterpret_cast<const float4*>(emb + bk * DIM + w * 16);
    float* outp = out + b * (DIM * HW) + hw0;
    float lsum = 0.f;
#pragma unroll
    for (int i = 0; i < 4; ++i) {
        const float4 q = eq[i];
        const int c0 = w * 16 + 4 * i;
        const float4 xq = *(const float4*)(xs + l * XSTR + c0);  // aligned (c0 % 4 == 0)
        const float d0 = q.x - xq.x, d1 = q.y - xq.y;
        const float d2 = q.z - xq.z, d3 = q.w - xq.w;
        lsum += d0 * d0 + d1 * d1 + d2 * d2 + d3 * d3;
        outp[(c0 + 0) * HW + l] = xq.x + d0;   // STE: x + (q - x)
        outp[(c0 + 1) * HW + l] = xq.y + d1;
        outp[(c0 + 2) * HW + l] = xq.z + d2;
        outp[(c0 + 3) * HW + l] = xq.w + d3;
    }

#pragma unroll
    for (int off = 32; off; off >>= 1) lsum += __shfl_down(lsum, off, 64);
    if (l == 0) lred[w] = lsum;
    __syncthreads();
    if (t == 0)
        atomicAdd(ws + WS_LOSS, (lred[0] + lred[1]) + (lred[2] + lred[3]));
}

__global__ void vq_final(float* __restrict__ out, const float* __restrict__ ws) {
    __shared__ float red[16];
    const int t = threadIdx.x;  // 1024 threads
    const unsigned int* counts = reinterpret_cast<const unsigned int*>(ws) + WS_CNT;
    float p = (float)counts[t] * (1.0f / 65536.f);
    float v = p * logf(p + 1e-10f);
#pragma unroll
    for (int off = 32; off; off >>= 1) v += __shfl_down(v, off, 64);
    if ((t & 63) == 0) red[t >> 6] = v;
    __syncthreads();
    if (t == 0) {
        float s = 0.f;
#pragma unroll
        for (int i = 0; i < 16; ++i) s += red[i];
        out[OUT_ELEMS]     = 0.25f * (1.0f / (float)OUT_ELEMS) * ws[WS_LOSS];
        out[OUT_ELEMS + 1] = expf(-s);
    }
}

extern "C" void kernel_launch(void* const* d_in, const int* in_sizes, int n_in,
                              void* d_out, int out_size, void* d_ws, size_t ws_size,
                              hipStream_t stream) {
    const float* in  = (const float*)d_in[0];
    const float* emb = (const float*)d_in[1];
    float* out = (float*)d_out;
    float* ws  = (float*)d_ws;

    vq_init<<<4, 256, 0, stream>>>(emb, ws);
    vq_main<<<N_ROWS / 64, 256, 0, stream>>>(in, emb, out, ws);
    vq_final<<<1, 1024, 0, stream>>>(out, ws);
}

// Round 8
// 174.817 us; speedup vs baseline: 2.7845x; 2.7845x over previous
//
#include <hip/hip_runtime.h>
#include <stdint.h>

// VectorQuantizer (eval fwd): inputs [64,64,32,32] f32 NCHW, embedding [1024,64] f32.
// Outputs concatenated: quantized [64,64,32,32] f32, loss scalar, perplexity scalar.
//
// Round-8: round-7 fused structure + readfirstlane fix.
//  Round 7 derived the wave's k-range from threadIdx.x>>6, which LLVM treats as
//  DIVERGENT -> e loads compiled to per-lane VMEM broadcasts (SGPR_Count fell
//  112->32, VALUBusy 24%). readfirstlane forces the wave id into an SGPR ->
//  e/e2 addresses uniform -> s_load (scalar pipe) -> inner loop is pure
//  v_fma(SGPR e, VGPR x) with x chunks ds_read from the LDS tile.
// Distance arithmetic unchanged: dist = ||e||^2 - 2 x.e (bit-exact selections,
// passed absmax 0.0 in rounds 2/3/5/6/7).

#define K_CODES 1024
#define DIM 64
#define HW 1024          // 32*32
#define N_ROWS 65536
#define OUT_ELEMS 4194304
#define XSTR 68          // x row stride in dwords

// ws layout (float indices)
#define WS_E2   0        // 1024 f32: ||e_k||^2
#define WS_CNT  1024     // 1024 u32: counts
#define WS_LOSS 2048     // 1 f32

__global__ void vq_init(const float* __restrict__ emb, float* __restrict__ ws) {
    const int k = blockIdx.x * blockDim.x + threadIdx.x;  // 1024 threads total
    if (k < K_CODES) {
        const float4* e4 = reinterpret_cast<const float4*>(emb + k * DIM);
        float s = 0.f;
#pragma unroll
        for (int i = 0; i < DIM / 4; ++i) {
            float4 v = e4[i];
            s += v.x * v.x + v.y * v.y + v.z * v.z + v.w * v.w;
        }
        ws[WS_E2 + k] = s;
        reinterpret_cast<unsigned int*>(ws)[WS_CNT + k] = 0u;
    }
    if (blockIdx.x == 0 && threadIdx.x == 0) ws[WS_LOSS] = 0.f;
}

__global__ __launch_bounds__(256, 4) void vq_main(
    const float* __restrict__ in, const float* __restrict__ emb,
    float* __restrict__ out, float* __restrict__ ws)
{
    __shared__ __align__(16) float xs[64 * XSTR];   // 17408 B
    __shared__ float bwd[4][64];
    __shared__ int   bwk[4][64];
    __shared__ int   fk[64];
    __shared__ float lred[4];

    const int t = threadIdx.x;
    const int w = t >> 6;        // wave id (divergent in LLVM's analysis)
    const int l = t & 63;        // pixel-row within block
    // Force wave-uniformity: w_u lives in an SGPR -> all addresses derived
    // from it are scalar -> e/e2 go through s_load on the scalar pipe.
    const int w_u = __builtin_amdgcn_readfirstlane(w);

    const int row0 = blockIdx.x * 64;
    const int b = row0 >> 10, hw0 = row0 & 1023;
    const float* xin = in + b * (DIM * HW) + hw0;

    // ---- stage x tile: thread (w,l) loads channels [16w,16w+16) of row l ----
#pragma unroll
    for (int cc = 0; cc < 16; ++cc) {
        const int c = w * 16 + cc;
        xs[l * XSTR + c] = xin[c * HW + l];   // lanes l consecutive -> coalesced
    }
    __syncthreads();

    // ---- argmin over this wave's 256 codes (k0 wave-uniform) ----
    const float* e2 = ws + WS_E2;
    const float* xrow = xs + l * XSTR;
    float best = 3.4e38f;
    int   bestk = 0;
    const int k0 = w_u * 256;

    for (int kg = 0; kg < 256; kg += 8) {
        float acc[8] = {0.f, 0.f, 0.f, 0.f, 0.f, 0.f, 0.f, 0.f};
#pragma unroll
        for (int ch = 0; ch < 8; ++ch) {
            float xc[8];
            *(float4*)(xc)     = *(const float4*)(xrow + ch * 8);      // ds_read_b128
            *(float4*)(xc + 4) = *(const float4*)(xrow + ch * 8 + 4);  // ds_read_b128
#pragma unroll
            for (int c = 0; c < 8; ++c) {
                const float* e = emb + (k0 + kg + c) * DIM + ch * 8;   // uniform -> s_load
#pragma unroll
                for (int j = 0; j < 8; ++j)
                    acc[c] = fmaf(e[j], xc[j], acc[c]);
            }
        }
#pragma unroll
        for (int c = 0; c < 8; ++c) {
            const int k = k0 + kg + c;
            const float dist = fmaf(-2.f, acc[c], e2[k]);
            if (dist < best) { best = dist; bestk = k; }   // strict < : first occurrence
        }
    }

    bwd[w][l] = best;
    bwk[w][l] = bestk;
    __syncthreads();

    // ---- lex-merge across the 4 waves (k-ranges ascending) ----
    if (t < 64) {
        float bb = bwd[0][t]; int bk = bwk[0][t];
#pragma unroll
        for (int s = 1; s < 4; ++s) {
            const float d = bwd[s][t]; const int k = bwk[s][t];
            if (d < bb || (d == bb && k < bk)) { bb = d; bk = k; }
        }
        fk[t] = bk;
        atomicAdd(reinterpret_cast<unsigned int*>(ws) + WS_CNT + bk, 1u);
    }
    __syncthreads();

    // ---- fused epilogue: thread (w,l): row l, channels [16w,16w+16) ----
    const int bk = fk[l];
    const float4* eq = reinterpret_cast<const float4*>(emb + bk * DIM + w * 16);
    float* outp = out + b * (DIM * HW) + hw0;
    float lsum = 0.f;
#pragma unroll
    for (int i = 0; i < 4; ++i) {
        const float4 q = eq[i];
        const int c0 = w * 16 + 4 * i;
        const float4 xq = *(const float4*)(xs + l * XSTR + c0);  // aligned (c0 % 4 == 0)
        const float d0 = q.x - xq.x, d1 = q.y - xq.y;
        const float d2 = q.z - xq.z, d3 = q.w - xq.w;
        lsum += d0 * d0 + d1 * d1 + d2 * d2 + d3 * d3;
        outp[(c0 + 0) * HW + l] = xq.x + d0;   // STE: x + (q - x)
        outp[(c0 + 1) * HW + l] = xq.y + d1;
        outp[(c0 + 2) * HW + l] = xq.z + d2;
        outp[(c0 + 3) * HW + l] = xq.w + d3;
    }

#pragma unroll
    for (int off = 32; off; off >>= 1) lsum += __shfl_down(lsum, off, 64);
    if (l == 0) lred[w] = lsum;
    __syncthreads();
    if (t == 0)
        atomicAdd(ws + WS_LOSS, (lred[0] + lred[1]) + (lred[2] + lred[3]));
}

__global__ void vq_final(float* __restrict__ out, const float* __restrict__ ws) {
    __shared__ float red[16];
    const int t = threadIdx.x;  // 1024 threads
    const unsigned int* counts = reinterpret_cast<const unsigned int*>(ws) + WS_CNT;
    float p = (float)counts[t] * (1.0f / 65536.f);
    float v = p * logf(p + 1e-10f);
#pragma unroll
    for (int off = 32; off; off >>= 1) v += __shfl_down(v, off, 64);
    if ((t & 63) == 0) red[t >> 6] = v;
    __syncthreads();
    if (t == 0) {
        float s = 0.f;
#pragma unroll
        for (int i = 0; i < 16; ++i) s += red[i];
        out[OUT_ELEMS]     = 0.25f * (1.0f / (float)OUT_ELEMS) * ws[WS_LOSS];
        out[OUT_ELEMS + 1] = expf(-s);
    }
}

extern "C" void kernel_launch(void* const* d_in, const int* in_sizes, int n_in,
                              void* d_out, int out_size, void* d_ws, size_t ws_size,
                              hipStream_t stream) {
    const float* in  = (const float*)d_in[0];
    const float* emb = (const float*)d_in[1];
    float* out = (float*)d_out;
    float* ws  = (float*)d_ws;

    vq_init<<<4, 256, 0, stream>>>(emb, ws);
    vq_main<<<N_ROWS / 64, 256, 0, stream>>>(in, emb, out, ws);
    vq_final<<<1, 1024, 0, stream>>>(out, ws);
}